// Round 14
// baseline (310.528 us; speedup 1.0000x reference)
//
#include <hip/hip_runtime.h>
#include <hip/hip_fp16.h>

#define N_NODES 100000
#define N_GRAPHS 64
#define BN_EPS 1e-5

#define NBF 391      // fine buckets of 256 nodes
#define PT1 4096
#define CAPF 4608    // per-bucket capacity (mean 4092, sigma~64 -> 8 sigma)

typedef _Float16 f16x8 __attribute__((ext_vector_type(8)));
typedef float f32x4 __attribute__((ext_vector_type(4)));

union F16x8u {
    f16x8 v;
    __half2 h2[4];
    uint4 u;
};

__device__ __forceinline__ float bfly64(float v) {
#pragma unroll
    for (int m = 1; m < 64; m <<= 1) v += __shfl_xor(v, m, 64);
    return v;
}

__device__ __forceinline__ unsigned pack_h2(float a, float b) {
    __half2 h = __floats2half2_rn(a, b);
    unsigned w;
    __builtin_memcpy(&w, &h, 4);
    return w;
}

__device__ __forceinline__ float2 unpack_h2(unsigned w) {
    __half2 h;
    __builtin_memcpy(&h, &w, 4);
    return __half22float2(h);
}

// ---------------- weight packing + cursor init + zero-init (fused) ----------------
// frag[kb][cb][lane][i] holds W[kb*32 + (lane>>4)*8 + i][cb*16 + (lane&15)].
__global__ __launch_bounds__(256)
void pack_w(const float* __restrict__ Wl2, const float* __restrict__ Wr2,
            const float* __restrict__ Wl3, const float* __restrict__ Wr3,
            __half* __restrict__ pk, int* __restrict__ fcur,
            double* __restrict__ zero_region) {
    int tid = threadIdx.x;
    if (blockIdx.x == 0) {
        for (int t = tid; t < NBF; t += 256) fcur[t] = t * CAPF;
    } else if (blockIdx.x <= 4) {
        // zero sums (768 dbl) + pooledd (8192 dbl) = 8960 doubles, contiguous
        for (int i = (blockIdx.x - 1) * 256 + tid; i < 8960; i += 1024)
            zero_region[i] = 0.0;
    }
    int e = blockIdx.x * 256 + tid;   // grid is exactly 80*256 = 20480
    const float* W; int le, DOUT, NCB, base, SZ;
    if (e < 2048)       { W = Wl2; le = e;         DOUT = 64;  NCB = 4; base = 0;     SZ = 2048; }
    else if (e < 4096)  { W = Wr2; le = e - 2048;  DOUT = 64;  NCB = 4; base = 4096;  SZ = 2048; }
    else if (e < 12288) { W = Wl3; le = e - 4096;  DOUT = 128; NCB = 8; base = 8192;  SZ = 8192; }
    else                { W = Wr3; le = e - 12288; DOUT = 128; NCB = 8; base = 24576; SZ = 8192; }
    int i = le & 7;
    int lane = (le >> 3) & 63;
    int cbkb = le >> 9;
    int cb = cbkb % NCB;
    int kb = cbkb / NCB;
    int k = kb * 32 + ((lane >> 4) << 3) + i;
    int col = cb * 16 + (lane & 15);
    float w = W[k * DOUT + col];
    __half h = __float2half(w);
    float lo = w - __half2float(h);
    pk[base + le] = h;
    pk[base + SZ + le] = __float2half(lo);
}

// Packed edge word: bits 0..16 = src (N < 2^17), bits 17..24 = dst & 255.
// Bucket id (dst >> 8) is implied by the region the word lives in.

// ---------------- single-pass partition: edges -> 391 fine buckets ----------------
__global__ __launch_bounds__(256)
void part1(const int* __restrict__ dst, const int* __restrict__ src,
           int* __restrict__ fcur, int* __restrict__ qpk, int E) {
    __shared__ int ld[PT1];
    __shared__ unsigned short lb[PT1];
    __shared__ int hist[NBF], lbase[NBF], gbase[NBF];
    __shared__ int pairs[256];
    long long t0 = (long long)blockIdx.x * PT1;
    int n = (int)min((long long)PT1, (long long)E - t0);
    int tid = threadIdx.x;
    for (int i = tid; i < NBF; i += 256) hist[i] = 0;
    __syncthreads();
    int p[PT1 / 256], c[PT1 / 256];
#pragma unroll
    for (int k = 0; k < PT1 / 256; ++k) {
        int li = k * 256 + tid;
        if (li < n) {
            int d = __builtin_nontemporal_load(dst + t0 + li);
            int s = __builtin_nontemporal_load(src + t0 + li);
            c[k] = d >> 8;
            p[k] = ((d & 255) << 17) | s;
            atomicAdd(&hist[c[k]], 1);
        }
    }
    __syncthreads();
    // exclusive prefix over NBF entries via pair-scan (256 threads, 2 entries each)
    int h0 = (2 * tid < NBF) ? hist[2 * tid] : 0;
    int h1 = (2 * tid + 1 < NBF) ? hist[2 * tid + 1] : 0;
    pairs[tid] = h0 + h1;
    __syncthreads();
    for (int st = 1; st < 256; st <<= 1) {
        int v = (tid >= st) ? pairs[tid - st] : 0;
        __syncthreads();
        pairs[tid] += v;
        __syncthreads();
    }
    int pe = tid ? pairs[tid - 1] : 0;
    if (2 * tid < NBF) lbase[2 * tid] = pe;
    if (2 * tid + 1 < NBF) lbase[2 * tid + 1] = pe + h0;
    __syncthreads();
    for (int b = tid; b < NBF; b += 256)
        gbase[b] = atomicAdd(&fcur[b], hist[b]);
    __syncthreads();
    for (int i = tid; i < NBF; i += 256) hist[i] = 0;
    __syncthreads();
#pragma unroll
    for (int k = 0; k < PT1 / 256; ++k) {
        int li = k * 256 + tid;
        if (li < n) {
            int pos = lbase[c[k]] + atomicAdd(&hist[c[k]], 1);
            ld[pos] = p[k]; lb[pos] = (unsigned short)c[k];
        }
    }
    __syncthreads();
    for (int i = tid; i < n; i += 256) {
        int bb = lb[i];
        int g = gbase[bb] + (i - lbase[bb]);
        qpk[g] = ld[i];
    }
}

// ---------------- per-bucket CSR finalize (256 nodes/bucket; emits beg + end) ----------------
__global__ __launch_bounds__(256)
void fill_final(const int* __restrict__ qpk, const int* __restrict__ fcur,
                int* __restrict__ offs, int* __restrict__ oend,
                int* __restrict__ nbr, int N) {
    __shared__ int cnt[256], cbase[256], cur[256];
    __shared__ int lout[CAPF];
    int b = blockIdx.x;
    int nlo = b << 8;
    int nn = min(256, N - nlo);
    int ebeg = b * CAPF;
    int ne = fcur[b] - ebeg;    // final cursor - base = count
    int tid = threadIdx.x;
    cnt[tid] = 0; cur[tid] = 0;
    __syncthreads();
    for (int i = tid; i < ne; i += 256)
        atomicAdd(&cnt[(qpk[ebeg + i] >> 17) & 255], 1);
    __syncthreads();
    cbase[tid] = cnt[tid];
    __syncthreads();
    for (int st = 1; st < 256; st <<= 1) {
        int v = (tid >= st) ? cbase[tid - st] : 0;
        __syncthreads();
        cbase[tid] += v;
        __syncthreads();
    }
    if (tid < nn) {
        offs[nlo + tid] = ebeg + (tid ? cbase[tid - 1] : 0);
        oend[nlo + tid] = ebeg + cbase[tid];
    }
    __syncthreads();
    for (int i = tid; i < ne; i += 256) {
        int p = qpk[ebeg + i];
        int ln = (p >> 17) & 255;
        int pos = (ln ? cbase[ln - 1] : 0) + atomicAdd(&cur[ln], 1);
        lout[pos] = p & 0x1FFFF;
    }
    __syncthreads();
    for (int i = tid; i < ne; i += 256)
        nbr[ebeg + i] = lout[i];
}

// ---------------- layer 1 fused: agg + linear + BN stats; fp16 h1 out ----------------
__global__ __launch_bounds__(256)
void layer1_fused(const float2* __restrict__ x2,
                  const int* __restrict__ offs, const int* __restrict__ oend,
                  const int* __restrict__ nbr,
                  const float* __restrict__ Wl, const float* __restrict__ bl,
                  const float* __restrict__ Wr,
                  __half* __restrict__ hout16,
                  double* __restrict__ sums, int N) {
    __shared__ float sAr[64];
    int tid = threadIdx.x;
    if (tid < 64) sAr[tid] = 0.f;
    __syncthreads();
    int n = blockIdx.x * 256 + tid;
    bool valid = (n < N);
    int beg = 0, end = 0;
    if (valid) { beg = offs[n]; end = oend[n]; }
    float ax0 = 0.f, ay0 = 0.f, ax1 = 0.f, ay1 = 0.f;
    int j = beg;
    for (; j + 16 <= end; j += 16) {
        int s[16];
#pragma unroll
        for (int u = 0; u < 16; ++u) s[u] = __builtin_nontemporal_load(nbr + j + u);
        float2 v[16];
#pragma unroll
        for (int u = 0; u < 16; ++u) v[u] = x2[s[u]];
#pragma unroll
        for (int u = 0; u < 16; ++u) {
            if (u & 1) { ax1 += v[u].x; ay1 += v[u].y; }
            else       { ax0 += v[u].x; ay0 += v[u].y; }
        }
    }
    for (; j + 4 <= end; j += 4) {
        int s[4];
#pragma unroll
        for (int u = 0; u < 4; ++u) s[u] = __builtin_nontemporal_load(nbr + j + u);
        float2 v[4];
#pragma unroll
        for (int u = 0; u < 4; ++u) v[u] = x2[s[u]];
        ax0 += v[0].x; ay0 += v[0].y;
        ax1 += v[1].x; ay1 += v[1].y;
        ax0 += v[2].x; ay0 += v[2].y;
        ax1 += v[3].x; ay1 += v[3].y;
    }
    for (; j < end; ++j) {
        float2 v = x2[nbr[j]];
        ax0 += v.x; ay0 += v.y;
    }
    float invd = 1.0f / fmaxf((float)(end - beg), 1.0f);
    float a0 = (ax0 + ax1) * invd, a1 = (ay0 + ay1) * invd;
    float x0 = 0.f, x1 = 0.f;
    if (valid) {
        float2 xv = x2[n];
        x0 = xv.x; x1 = xv.y;
    }
    float acc[32];
#pragma unroll
    for (int jj = 0; jj < 32; ++jj)
        acc[jj] = bl[jj] + a0 * Wl[jj] + a1 * Wl[32 + jj] + x0 * Wr[jj] + x1 * Wr[32 + jj];
    if (valid) {
        unsigned w[16];
#pragma unroll
        for (int p = 0; p < 16; ++p) w[p] = pack_h2(acc[2*p], acc[2*p+1]);
        uint4* q = (uint4*)(hout16 + (size_t)n * 32);
        q[0] = make_uint4(w[0], w[1], w[2], w[3]);
        q[1] = make_uint4(w[4], w[5], w[6], w[7]);
        q[2] = make_uint4(w[8], w[9], w[10], w[11]);
        q[3] = make_uint4(w[12], w[13], w[14], w[15]);
    }
    int lane = tid & 63;
#pragma unroll
    for (int jj = 0; jj < 32; ++jj) {
        float v = valid ? acc[jj] : 0.f;
        float s = bfly64(v);
        float q = bfly64(v * v);
        if (lane == jj) atomicAdd(&sAr[jj], s);
        if (lane == 32 + jj) atomicAdd(&sAr[32 + jj], q);
    }
    __syncthreads();
    if (tid < 64) atomicAdd(&sums[tid], (double)sAr[tid]);
}

// ---------------- fused BN+ReLU gather agg: gathers raw h, applies BN inline,
// 16-deep MLP, fp32 dual-bank accum, mean out as fp16 ----------------
__device__ __forceinline__ void accum8_bn(float* acc, uint4 v,
                                          const float* sc, const float* sf) {
    float2 f0 = unpack_h2(v.x), f1 = unpack_h2(v.y);
    float2 f2 = unpack_h2(v.z), f3 = unpack_h2(v.w);
    acc[0] += fmaxf(f0.x * sc[0] + sf[0], 0.f);
    acc[1] += fmaxf(f0.y * sc[1] + sf[1], 0.f);
    acc[2] += fmaxf(f1.x * sc[2] + sf[2], 0.f);
    acc[3] += fmaxf(f1.y * sc[3] + sf[3], 0.f);
    acc[4] += fmaxf(f2.x * sc[4] + sf[4], 0.f);
    acc[5] += fmaxf(f2.y * sc[5] + sf[5], 0.f);
    acc[6] += fmaxf(f3.x * sc[6] + sf[6], 0.f);
    acc[7] += fmaxf(f3.y * sc[7] + sf[7], 0.f);
}

template<int F>
__global__ __launch_bounds__(256)
void agg_bn(const uint4* __restrict__ xh, const int* __restrict__ offs,
            const int* __restrict__ oend, const int* __restrict__ nbr,
            const double* __restrict__ sums, const float* __restrict__ gamma,
            const float* __restrict__ beta, uint4* __restrict__ aggh, int N) {
    constexpr int FV = F / 8;            // uint4 lanes per row
    constexpr int NPB = 256 / FV;        // nodes per block
    __shared__ float lsc[F], lsf[F];
    int tid = threadIdx.y * FV + threadIdx.x;
    if (tid < F) {
        double mu = sums[tid] / (double)N_NODES;
        double var = sums[F + tid] / (double)N_NODES - mu * mu;
        if (var < 0.0) var = 0.0;
        double sc = (double)gamma[tid] / sqrt(var + BN_EPS);
        lsc[tid] = (float)sc;
        lsf[tid] = (float)((double)beta[tid] - mu * sc);
    }
    __syncthreads();
    int n = blockIdx.x * NPB + threadIdx.y;
    if (n >= N) return;
    int f = threadIdx.x;
    float sc[8], sf[8];
#pragma unroll
    for (int q = 0; q < 8; ++q) { sc[q] = lsc[f * 8 + q]; sf[q] = lsf[f * 8 + q]; }
    int beg = offs[n], end = oend[n];
    float a0[8], a1[8];
#pragma unroll
    for (int q = 0; q < 8; ++q) { a0[q] = 0.f; a1[q] = 0.f; }
    int j = beg;
    // 16-deep main loop: 16 independent gathers in flight per thread
    for (; j + 16 <= end; j += 16) {
        int s[16];
#pragma unroll
        for (int u = 0; u < 16; ++u) s[u] = __builtin_nontemporal_load(nbr + j + u);
        uint4 v[16];
#pragma unroll
        for (int u = 0; u < 16; ++u) v[u] = xh[s[u] * FV + f];
#pragma unroll
        for (int u = 0; u < 16; ++u)
            accum8_bn((u & 1) ? a1 : a0, v[u], sc, sf);
    }
    if (j + 8 <= end) {
        int s[8];
#pragma unroll
        for (int u = 0; u < 8; ++u) s[u] = __builtin_nontemporal_load(nbr + j + u);
        uint4 v[8];
#pragma unroll
        for (int u = 0; u < 8; ++u) v[u] = xh[s[u] * FV + f];
#pragma unroll
        for (int u = 0; u < 8; ++u)
            accum8_bn((u & 1) ? a1 : a0, v[u], sc, sf);
        j += 8;
    }
    if (j + 4 <= end) {
        int s[4];
#pragma unroll
        for (int u = 0; u < 4; ++u) s[u] = __builtin_nontemporal_load(nbr + j + u);
        uint4 v[4];
#pragma unroll
        for (int u = 0; u < 4; ++u) v[u] = xh[s[u] * FV + f];
#pragma unroll
        for (int u = 0; u < 4; ++u)
            accum8_bn((u & 1) ? a1 : a0, v[u], sc, sf);
        j += 4;
    }
    for (; j < end; ++j) {
        uint4 v = xh[__builtin_nontemporal_load(nbr + j) * FV + f];
        accum8_bn(a0, v, sc, sf);
    }
    float invd = 1.0f / fmaxf((float)(end - beg), 1.0f);
    uint4 o;
    o.x = pack_h2((a0[0] + a1[0]) * invd, (a0[1] + a1[1]) * invd);
    o.y = pack_h2((a0[2] + a1[2]) * invd, (a0[3] + a1[3]) * invd);
    o.z = pack_h2((a0[4] + a1[4]) * invd, (a0[5] + a1[5]) * invd);
    o.w = pack_h2((a0[6] + a1[6]) * invd, (a0[7] + a1[7]) * invd);
    aggh[n * FV + f] = o;
}

// ---------------- MFMA linear: fp16 fragments (agg pre-scaled; x = raw h with inline BN),
// split-fp16 weights, fp32 MFMA accumulate, fp16 out, fused BN-stats partials ----------------
template<int DIN, int DOUT>
__global__ __launch_bounds__(256)
void linear_mfma(const __half* __restrict__ xh, const __half* __restrict__ agg16,
                 const __half* __restrict__ wlhi, const __half* __restrict__ wllo,
                 const __half* __restrict__ wrhi, const __half* __restrict__ wrlo,
                 const float* __restrict__ bl,
                 const double* __restrict__ sumsIn,
                 const float* __restrict__ gIn, const float* __restrict__ beIn,
                 __half* __restrict__ hout16, float* __restrict__ partial, int N) {
    constexpr int KB = DIN / 32;    // K-slabs of 32
    constexpr int NCB = DOUT / 16;  // col-blocks of 16
    constexpr int MREP = 2;         // 16-row fragments per wave
    constexpr int MB = 4 * MREP * 16;  // 128 rows per block
    __shared__ float blkS[DOUT], blkQ[DOUT];
    __shared__ __align__(16) float lscIn[DIN], lsfIn[DIN];
    int tid = threadIdx.x;
    if (tid < DIN) {
        double mu = sumsIn[tid] / (double)N_NODES;
        double var = sumsIn[DIN + tid] / (double)N_NODES - mu * mu;
        if (var < 0.0) var = 0.0;
        double sc = (double)gIn[tid] / sqrt(var + BN_EPS);
        lscIn[tid] = (float)sc;
        lsfIn[tid] = (float)((double)beIn[tid] - mu * sc);
    }
    for (int i = tid; i < DOUT; i += 256) { blkS[i] = 0.f; blkQ[i] = 0.f; }
    __syncthreads();
    int n0 = blockIdx.x * MB;

    int wave = tid >> 6;
    int lane = tid & 63;
    int rlane = lane & 15;
    int kg = lane >> 4;          // 0..3 -> k-group of 8
    int rbase = n0 + wave * (MREP * 16);

    // ---- A fragments: agg pure loads; x with inline BN+ReLU ----
    f16x8 aA[MREP][KB], aX[MREP][KB];
#pragma unroll
    for (int m = 0; m < MREP; ++m) {
        int row = rbase + m * 16 + rlane;
        int rowc = min(row, N - 1);
#pragma unroll
        for (int kb = 0; kb < KB; ++kb) {
            int c0 = kb * 32 + kg * 8;
            F16x8u ta, tx;
            ta.u = *(const uint4*)(agg16 + (size_t)rowc * DIN + c0);
            tx.u = *(const uint4*)(xh + (size_t)rowc * DIN + c0);
            float4 sca = ((const float4*)lscIn)[c0 >> 2];
            float4 scb = ((const float4*)lscIn)[(c0 >> 2) + 1];
            float4 sfa = ((const float4*)lsfIn)[c0 >> 2];
            float4 sfb = ((const float4*)lsfIn)[(c0 >> 2) + 1];
            float2 f0 = __half22float2(tx.h2[0]);
            float2 f1 = __half22float2(tx.h2[1]);
            float2 f2 = __half22float2(tx.h2[2]);
            float2 f3 = __half22float2(tx.h2[3]);
            tx.h2[0] = __floats2half2_rn(fmaxf(f0.x * sca.x + sfa.x, 0.f),
                                         fmaxf(f0.y * sca.y + sfa.y, 0.f));
            tx.h2[1] = __floats2half2_rn(fmaxf(f1.x * sca.z + sfa.z, 0.f),
                                         fmaxf(f1.y * sca.w + sfa.w, 0.f));
            tx.h2[2] = __floats2half2_rn(fmaxf(f2.x * scb.x + sfb.x, 0.f),
                                         fmaxf(f2.y * scb.y + sfb.y, 0.f));
            tx.h2[3] = __floats2half2_rn(fmaxf(f3.x * scb.z + sfb.z, 0.f),
                                         fmaxf(f3.y * scb.w + sfb.w, 0.f));
            aA[m][kb] = ta.v;
            aX[m][kb] = tx.v;
        }
    }

    // ---- accumulators init with bias (D layout: row=(lane>>4)*4+r, col=lane&15) ----
    f32x4 acc[MREP][NCB];
#pragma unroll
    for (int cb = 0; cb < NCB; ++cb) {
        float bv = bl[cb * 16 + rlane];
#pragma unroll
        for (int m = 0; m < MREP; ++m)
            acc[m][cb] = {bv, bv, bv, bv};
    }

    // ---- MFMA main: acc += aA*(Wl_hi+Wl_lo) + aX*(Wr_hi+Wr_lo) ----
#pragma unroll
    for (int cb = 0; cb < NCB; ++cb) {
#pragma unroll
        for (int kb = 0; kb < KB; ++kb) {
            size_t fo = ((size_t)(kb * NCB + cb) * 64 + lane) * 8;
            f16x8 blh = *(const f16x8*)(wlhi + fo);
            f16x8 bll = *(const f16x8*)(wllo + fo);
            f16x8 brh = *(const f16x8*)(wrhi + fo);
            f16x8 brl = *(const f16x8*)(wrlo + fo);
#pragma unroll
            for (int m = 0; m < MREP; ++m) {
                acc[m][cb] = __builtin_amdgcn_mfma_f32_16x16x32_f16(aA[m][kb], blh, acc[m][cb], 0, 0, 0);
                acc[m][cb] = __builtin_amdgcn_mfma_f32_16x16x32_f16(aA[m][kb], bll, acc[m][cb], 0, 0, 0);
                acc[m][cb] = __builtin_amdgcn_mfma_f32_16x16x32_f16(aX[m][kb], brh, acc[m][cb], 0, 0, 0);
                acc[m][cb] = __builtin_amdgcn_mfma_f32_16x16x32_f16(aX[m][kb], brl, acc[m][cb], 0, 0, 0);
            }
        }
    }

    // ---- store fp16 outputs ----
#pragma unroll
    for (int m = 0; m < MREP; ++m) {
        int rowb = rbase + m * 16 + kg * 4;
#pragma unroll
        for (int r = 0; r < 4; ++r) {
            int node = rowb + r;
            if (node < N) {
#pragma unroll
                for (int cb = 0; cb < NCB; ++cb)
                    hout16[(size_t)node * DOUT + cb * 16 + rlane] = __float2half(acc[m][cb][r]);
            }
        }
    }

    // ---- fused BN-stats partials: per-block sum/sumsq per feature ----
#pragma unroll
    for (int cb = 0; cb < NCB; ++cb) {
        float s = 0.f, q = 0.f;
#pragma unroll
        for (int m = 0; m < MREP; ++m) {
            int rowb = rbase + m * 16 + kg * 4;
#pragma unroll
            for (int r = 0; r < 4; ++r) {
                if (rowb + r < N) {
                    float v = acc[m][cb][r];
                    s += v; q += v * v;
                }
            }
        }
        s += __shfl_xor(s, 16, 64); s += __shfl_xor(s, 32, 64);
        q += __shfl_xor(q, 16, 64); q += __shfl_xor(q, 32, 64);
        if (kg == 0) {
            atomicAdd(&blkS[cb * 16 + rlane], s);
            atomicAdd(&blkQ[cb * 16 + rlane], q);
        }
    }
    __syncthreads();
    float* po = partial + (size_t)blockIdx.x * (2 * DOUT);
    for (int i = tid; i < DOUT; i += 256) {
        po[i] = blkS[i];
        po[DOUT + i] = blkQ[i];
    }
}

// ---------------- stats finalize: reduce P block-partials per feature in fp64, fixed order ----------------
template<int F>
__global__ __launch_bounds__(256)
void stats_finalize2(const float* __restrict__ partial, double* __restrict__ sums, int P) {
    __shared__ double sh[256];
    int i = blockIdx.x;
    int t = threadIdx.x;
    double a = 0.0;
    for (int k = t; k < P; k += 256)
        a += (double)partial[(size_t)k * (2 * F) + i];
    sh[t] = a;
    __syncthreads();
    for (int st = 128; st > 0; st >>= 1) {
        if (t < st) sh[t] += sh[t + st];
        __syncthreads();
    }
    if (t == 0) sums[i] = sh[0];
}

// ---------------- pool (fp16 h3) with inline BN3 finalize + fused ReLU ----------------
__global__ void pool_partial(const __half* __restrict__ h, const int* __restrict__ batch,
                             const double* __restrict__ sums,
                             const float* __restrict__ gamma, const float* __restrict__ beta,
                             double* __restrict__ pooled_d, int N) {
    __shared__ float lsc[128], lsf[128];
    const int CH = 64;
    int f = threadIdx.x;
    {
        double mu = sums[f] / (double)N_NODES;
        double var = sums[128 + f] / (double)N_NODES - mu * mu;
        if (var < 0.0) var = 0.0;
        double sc = (double)gamma[f] / sqrt(var + BN_EPS);
        lsc[f] = (float)sc;
        lsf[f] = (float)((double)beta[f] - mu * sc);
    }
    __syncthreads();
    int n0 = blockIdx.x * CH;
    if (n0 >= N) return;
    int n1 = min(n0 + CH, N);
    float sc = lsc[f], sf = lsf[f];
    int g = batch[n0];
    float acc = 0.f;
    for (int n = n0; n < n1; ++n) {
        int bg = batch[n];
        if (bg != g) {
            atomicAdd(&pooled_d[g * 128 + f], (double)acc);
            acc = 0.f;
            g = bg;
        }
        float v = __half2float(h[(long long)n * 128 + f]);
        acc += fmaxf(v * sc + sf, 0.f);
    }
    atomicAdd(&pooled_d[g * 128 + f], (double)acc);
}

// ---------------- fused pool-finalize + head MLP ----------------
__global__ void mlp_fused(const double* __restrict__ pooled_d, const int* __restrict__ batch,
                          const float* __restrict__ Wf1, const float* __restrict__ bf1,
                          const float* __restrict__ Wf2, const float* __restrict__ bf2,
                          float* __restrict__ out, int N) {
    __shared__ float sp[128];
    int g = blockIdx.x;
    int t = threadIdx.x;
    int lo = 0, hi = N;
    while (lo < hi) { int m = (lo + hi) >> 1; if (batch[m] < g) lo = m + 1; else hi = m; }
    int start = lo;
    hi = N;
    while (lo < hi) { int m = (lo + hi) >> 1; if (batch[m] < g + 1) lo = m + 1; else hi = m; }
    int cnt = lo - start;
    sp[t] = (float)(pooled_d[g * 128 + t] / (double)max(cnt, 1));
    __syncthreads();
    if (t < 64) {
        float hacc = bf1[t];
#pragma unroll 8
        for (int k = 0; k < 128; ++k) hacc += sp[k] * Wf1[k * 64 + t];
        hacc = fmaxf(hacc, 0.f) * Wf2[t];
        for (int o = 32; o > 0; o >>= 1) hacc += __shfl_down(hacc, o);
        if (t == 0) out[g] = hacc + bf2[0];
    }
}

extern "C" void kernel_launch(void* const* d_in, const int* in_sizes, int n_in,
                              void* d_out, int out_size, void* d_ws, size_t ws_size,
                              hipStream_t stream) {
    const float* x     = (const float*)d_in[0];
    const int*   ei    = (const int*)d_in[1];
    const int*   batch = (const int*)d_in[2];
    const float *Wl1=(const float*)d_in[3],  *bl1=(const float*)d_in[4],  *Wr1=(const float*)d_in[5];
    const float *g1 =(const float*)d_in[6],  *be1=(const float*)d_in[7];
    const float *Wl2=(const float*)d_in[8],  *bl2=(const float*)d_in[9],  *Wr2=(const float*)d_in[10];
    const float *g2 =(const float*)d_in[11], *be2=(const float*)d_in[12];
    const float *Wl3=(const float*)d_in[13], *bl3=(const float*)d_in[14], *Wr3=(const float*)d_in[15];
    const float *g3 =(const float*)d_in[16], *be3=(const float*)d_in[17];
    const float *Wf1=(const float*)d_in[18], *bf1=(const float*)d_in[19];
    const float *Wf2=(const float*)d_in[20], *bf2=(const float*)d_in[21];

    const int N = N_NODES;
    const int E = in_sizes[1] / 2;
    const int* src = ei;
    const int* dst = ei + E;

    char* ws = (char*)d_ws;
    size_t off = 0;
    auto salloc = [&](size_t bytes) {
        void* p = ws + off;
        off += (bytes + 255) & ~(size_t)255;
        return p;
    };
    // --- zeroed-in-pack_w region (must stay contiguous: sums then pooledd) ---
    double* sums    = (double*)salloc(768 * 8);                      // 6144 B (256-aligned)
    double* pooledd = (double*)salloc((size_t)N_GRAPHS * 128 * 8);   // 65536 B
    // --- rest ---
    int*    offs    = (int*)   salloc((size_t)N * 4);
    int*    oend    = (int*)   salloc((size_t)N * 4);
    int*    fcur    = (int*)   salloc((NBF + 1) * 4);
    int*    nbr     = (int*)   salloc((size_t)NBF * CAPF * 4);       // 7.2 MB (padded bucket regions)
    float*  partial = (float*) salloc((size_t)1024 * 256 * 4);       // 1 MB (stats partials)
    __half* pk      = (__half*)salloc((size_t)40960 * 2);            // 80 KB packed weights
    __half* h1h     = (__half*)salloc((size_t)(N + 256) * 32 * 2);   // 6.4 MB
    __half* h2h     = (__half*)salloc((size_t)(N + 256) * 64 * 2);   // 12.8 MB
    __half* h3h     = (__half*)salloc((size_t)(N + 256) * 128 * 2);  // 25.7 MB
    __half* aggh    = (__half*)salloc((size_t)(N + 256) * 64 * 2);   // 12.8 MB (hosts qpk early)
    (void)ws_size;

    double* sums1 = sums, *sums2 = sums + 256, *sums3 = sums + 512;
    int* qpk = (int*)aggh;                 // 391*CAPF*4 = 7.2 MB <= 12.8

    const __half *pwl2h = pk,         *pwl2l = pk + 2048;
    const __half *pwr2h = pk + 4096,  *pwr2l = pk + 6144;
    const __half *pwl3h = pk + 8192,  *pwl3l = pk + 16384;
    const __half *pwr3h = pk + 24576, *pwr3l = pk + 32768;

    // ---- weight packing + cursor init + zero-init (fused, tiny) ----
    pack_w<<<80, 256, 0, stream>>>(Wl2, Wr2, Wl3, Wr3, pk, fcur, sums);

    // ---- CSR build: single-pass partition into 391 fixed-capacity buckets ----
    part1<<<(E + PT1 - 1) / PT1, 256, 0, stream>>>(dst, src, fcur, qpk, E);
    fill_final<<<NBF, 256, 0, stream>>>(qpk, fcur, offs, oend, nbr, N);

    const int NL = (N + 255) / 256;
    const int NBLK = (N + 127) / 128;   // 782 blocks for linear_mfma

    // ---- layer 1: fused agg + linear + stats -> fp16 h1 ----
    layer1_fused<<<NL, 256, 0, stream>>>((const float2*)x, offs, oend, nbr,
                                          Wl1, bl1, Wr1, h1h, sums1, N);

    // ---- layer 2: BN1 applied inline in both agg gather and linear x-load ----
    agg_bn<32><<<(N + 63) / 64, dim3(4, 64), 0, stream>>>(
        (const uint4*)h1h, offs, oend, nbr, sums1, g1, be1, (uint4*)aggh, N);
    linear_mfma<32, 64><<<NBLK, 256, 0, stream>>>(
        h1h, (const __half*)aggh, pwl2h, pwl2l, pwr2h, pwr2l, bl2,
        sums1, g1, be1, h2h, partial, N);
    stats_finalize2<64><<<128, 256, 0, stream>>>(partial, sums2, NBLK);

    // ---- layer 3: BN2 applied inline ----
    agg_bn<64><<<(N + 31) / 32, dim3(8, 32), 0, stream>>>(
        (const uint4*)h2h, offs, oend, nbr, sums2, g2, be2, (uint4*)aggh, N);
    linear_mfma<64, 128><<<NBLK, 256, 0, stream>>>(
        h2h, (const __half*)aggh, pwl3h, pwl3l, pwr3h, pwr3l, bl3,
        sums2, g2, be2, h3h, partial, N);
    stats_finalize2<128><<<256, 256, 0, stream>>>(partial, sums3, NBLK);

    // ---- pool + head ----
    pool_partial<<<(N + 63) / 64, 128, 0, stream>>>(h3h, batch, sums3, g3, be3, pooledd, N);
    mlp_fused<<<N_GRAPHS, 128, 0, stream>>>(pooledd, batch, Wf1, bf1, Wf2, bf2, (float*)d_out, N);
}

// Round 15
// 304.917 us; speedup vs baseline: 1.0184x; 1.0184x over previous
//
#include <hip/hip_runtime.h>
#include <hip/hip_fp16.h>

#define N_NODES 100000
#define N_GRAPHS 64
#define BN_EPS 1e-5

#define NBF 391      // fine buckets of 256 nodes
#define PT1 4096
#define CAPF 4608    // per-bucket capacity (mean 4092, sigma~64 -> 8 sigma)

typedef _Float16 f16x8 __attribute__((ext_vector_type(8)));
typedef float f32x4 __attribute__((ext_vector_type(4)));

union F16x8u {
    f16x8 v;
    __half2 h2[4];
    uint4 u;
};

__device__ __forceinline__ float bfly64(float v) {
#pragma unroll
    for (int m = 1; m < 64; m <<= 1) v += __shfl_xor(v, m, 64);
    return v;
}

__device__ __forceinline__ unsigned pack_h2(float a, float b) {
    __half2 h = __floats2half2_rn(a, b);
    unsigned w;
    __builtin_memcpy(&w, &h, 4);
    return w;
}

__device__ __forceinline__ float2 unpack_h2(unsigned w) {
    __half2 h;
    __builtin_memcpy(&h, &w, 4);
    return __half22float2(h);
}

// ---------------- weight packing + cursor init + zero-init (fused) ----------------
// frag[kb][cb][lane][i] holds W[kb*32 + (lane>>4)*8 + i][cb*16 + (lane&15)].
__global__ __launch_bounds__(256)
void pack_w(const float* __restrict__ Wl2, const float* __restrict__ Wr2,
            const float* __restrict__ Wl3, const float* __restrict__ Wr3,
            __half* __restrict__ pk, int* __restrict__ fcur,
            double* __restrict__ zero_region) {
    int tid = threadIdx.x;
    if (blockIdx.x == 0) {
        for (int t = tid; t < NBF; t += 256) fcur[t] = t * CAPF;
    } else if (blockIdx.x <= 4) {
        // zero sums (768 dbl) + pooledd (8192 dbl) = 8960 doubles, contiguous
        for (int i = (blockIdx.x - 1) * 256 + tid; i < 8960; i += 1024)
            zero_region[i] = 0.0;
    }
    int e = blockIdx.x * 256 + tid;   // grid is exactly 80*256 = 20480
    const float* W; int le, DOUT, NCB, base, SZ;
    if (e < 2048)       { W = Wl2; le = e;         DOUT = 64;  NCB = 4; base = 0;     SZ = 2048; }
    else if (e < 4096)  { W = Wr2; le = e - 2048;  DOUT = 64;  NCB = 4; base = 4096;  SZ = 2048; }
    else if (e < 12288) { W = Wl3; le = e - 4096;  DOUT = 128; NCB = 8; base = 8192;  SZ = 8192; }
    else                { W = Wr3; le = e - 12288; DOUT = 128; NCB = 8; base = 24576; SZ = 8192; }
    int i = le & 7;
    int lane = (le >> 3) & 63;
    int cbkb = le >> 9;
    int cb = cbkb % NCB;
    int kb = cbkb / NCB;
    int k = kb * 32 + ((lane >> 4) << 3) + i;
    int col = cb * 16 + (lane & 15);
    float w = W[k * DOUT + col];
    __half h = __float2half(w);
    float lo = w - __half2float(h);
    pk[base + le] = h;
    pk[base + SZ + le] = __float2half(lo);
}

// Packed edge word: bits 0..16 = src (N < 2^17), bits 17..24 = dst & 255.
// Bucket id (dst >> 8) is implied by the region the word lives in.

// ---------------- single-pass partition: edges -> 391 fine buckets ----------------
__global__ __launch_bounds__(256)
void part1(const int* __restrict__ dst, const int* __restrict__ src,
           int* __restrict__ fcur, int* __restrict__ qpk, int E) {
    __shared__ int ld[PT1];
    __shared__ unsigned short lb[PT1];
    __shared__ int hist[NBF], lbase[NBF], gbase[NBF];
    __shared__ int pairs[256];
    long long t0 = (long long)blockIdx.x * PT1;
    int n = (int)min((long long)PT1, (long long)E - t0);
    int tid = threadIdx.x;
    for (int i = tid; i < NBF; i += 256) hist[i] = 0;
    __syncthreads();
    int p[PT1 / 256], c[PT1 / 256];
#pragma unroll
    for (int k = 0; k < PT1 / 256; ++k) {
        int li = k * 256 + tid;
        if (li < n) {
            int d = __builtin_nontemporal_load(dst + t0 + li);
            int s = __builtin_nontemporal_load(src + t0 + li);
            c[k] = d >> 8;
            p[k] = ((d & 255) << 17) | s;
            atomicAdd(&hist[c[k]], 1);
        }
    }
    __syncthreads();
    // exclusive prefix over NBF entries via pair-scan (256 threads, 2 entries each)
    int h0 = (2 * tid < NBF) ? hist[2 * tid] : 0;
    int h1 = (2 * tid + 1 < NBF) ? hist[2 * tid + 1] : 0;
    pairs[tid] = h0 + h1;
    __syncthreads();
    for (int st = 1; st < 256; st <<= 1) {
        int v = (tid >= st) ? pairs[tid - st] : 0;
        __syncthreads();
        pairs[tid] += v;
        __syncthreads();
    }
    int pe = tid ? pairs[tid - 1] : 0;
    if (2 * tid < NBF) lbase[2 * tid] = pe;
    if (2 * tid + 1 < NBF) lbase[2 * tid + 1] = pe + h0;
    __syncthreads();
    for (int b = tid; b < NBF; b += 256)
        gbase[b] = atomicAdd(&fcur[b], hist[b]);
    __syncthreads();
    for (int i = tid; i < NBF; i += 256) hist[i] = 0;
    __syncthreads();
#pragma unroll
    for (int k = 0; k < PT1 / 256; ++k) {
        int li = k * 256 + tid;
        if (li < n) {
            int pos = lbase[c[k]] + atomicAdd(&hist[c[k]], 1);
            ld[pos] = p[k]; lb[pos] = (unsigned short)c[k];
        }
    }
    __syncthreads();
    for (int i = tid; i < n; i += 256) {
        int bb = lb[i];
        int g = gbase[bb] + (i - lbase[bb]);
        qpk[g] = ld[i];
    }
}

// ---------------- per-bucket CSR finalize (256 nodes/bucket; emits beg + end) ----------------
__global__ __launch_bounds__(256)
void fill_final(const int* __restrict__ qpk, const int* __restrict__ fcur,
                int* __restrict__ offs, int* __restrict__ oend,
                int* __restrict__ nbr, int N) {
    __shared__ int cnt[256], cbase[256], cur[256];
    __shared__ int lout[CAPF];
    int b = blockIdx.x;
    int nlo = b << 8;
    int nn = min(256, N - nlo);
    int ebeg = b * CAPF;
    int ne = fcur[b] - ebeg;    // final cursor - base = count
    int tid = threadIdx.x;
    cnt[tid] = 0; cur[tid] = 0;
    __syncthreads();
    for (int i = tid; i < ne; i += 256)
        atomicAdd(&cnt[(qpk[ebeg + i] >> 17) & 255], 1);
    __syncthreads();
    cbase[tid] = cnt[tid];
    __syncthreads();
    for (int st = 1; st < 256; st <<= 1) {
        int v = (tid >= st) ? cbase[tid - st] : 0;
        __syncthreads();
        cbase[tid] += v;
        __syncthreads();
    }
    if (tid < nn) {
        offs[nlo + tid] = ebeg + (tid ? cbase[tid - 1] : 0);
        oend[nlo + tid] = ebeg + cbase[tid];
    }
    __syncthreads();
    for (int i = tid; i < ne; i += 256) {
        int p = qpk[ebeg + i];
        int ln = (p >> 17) & 255;
        int pos = (ln ? cbase[ln - 1] : 0) + atomicAdd(&cur[ln], 1);
        lout[pos] = p & 0x1FFFF;
    }
    __syncthreads();
    for (int i = tid; i < ne; i += 256)
        nbr[ebeg + i] = lout[i];
}

// ---------------- layer 1 fused: agg + linear + BN stats; fp16 h1 out ----------------
__global__ __launch_bounds__(256)
void layer1_fused(const float2* __restrict__ x2,
                  const int* __restrict__ offs, const int* __restrict__ oend,
                  const int* __restrict__ nbr,
                  const float* __restrict__ Wl, const float* __restrict__ bl,
                  const float* __restrict__ Wr,
                  __half* __restrict__ hout16,
                  double* __restrict__ sums, int N) {
    __shared__ float sAr[64];
    int tid = threadIdx.x;
    if (tid < 64) sAr[tid] = 0.f;
    __syncthreads();
    int n = blockIdx.x * 256 + tid;
    bool valid = (n < N);
    int beg = 0, end = 0;
    if (valid) { beg = offs[n]; end = oend[n]; }
    float ax0 = 0.f, ay0 = 0.f, ax1 = 0.f, ay1 = 0.f;
    int j = beg;
    for (; j + 16 <= end; j += 16) {
        int s[16];
#pragma unroll
        for (int u = 0; u < 16; ++u) s[u] = __builtin_nontemporal_load(nbr + j + u);
        float2 v[16];
#pragma unroll
        for (int u = 0; u < 16; ++u) v[u] = x2[s[u]];
#pragma unroll
        for (int u = 0; u < 16; ++u) {
            if (u & 1) { ax1 += v[u].x; ay1 += v[u].y; }
            else       { ax0 += v[u].x; ay0 += v[u].y; }
        }
    }
    for (; j + 4 <= end; j += 4) {
        int s[4];
#pragma unroll
        for (int u = 0; u < 4; ++u) s[u] = __builtin_nontemporal_load(nbr + j + u);
        float2 v[4];
#pragma unroll
        for (int u = 0; u < 4; ++u) v[u] = x2[s[u]];
        ax0 += v[0].x; ay0 += v[0].y;
        ax1 += v[1].x; ay1 += v[1].y;
        ax0 += v[2].x; ay0 += v[2].y;
        ax1 += v[3].x; ay1 += v[3].y;
    }
    for (; j < end; ++j) {
        float2 v = x2[nbr[j]];
        ax0 += v.x; ay0 += v.y;
    }
    float invd = 1.0f / fmaxf((float)(end - beg), 1.0f);
    float a0 = (ax0 + ax1) * invd, a1 = (ay0 + ay1) * invd;
    float x0 = 0.f, x1 = 0.f;
    if (valid) {
        float2 xv = x2[n];
        x0 = xv.x; x1 = xv.y;
    }
    float acc[32];
#pragma unroll
    for (int jj = 0; jj < 32; ++jj)
        acc[jj] = bl[jj] + a0 * Wl[jj] + a1 * Wl[32 + jj] + x0 * Wr[jj] + x1 * Wr[32 + jj];
    if (valid) {
        unsigned w[16];
#pragma unroll
        for (int p = 0; p < 16; ++p) w[p] = pack_h2(acc[2*p], acc[2*p+1]);
        uint4* q = (uint4*)(hout16 + (size_t)n * 32);
        q[0] = make_uint4(w[0], w[1], w[2], w[3]);
        q[1] = make_uint4(w[4], w[5], w[6], w[7]);
        q[2] = make_uint4(w[8], w[9], w[10], w[11]);
        q[3] = make_uint4(w[12], w[13], w[14], w[15]);
    }
    int lane = tid & 63;
#pragma unroll
    for (int jj = 0; jj < 32; ++jj) {
        float v = valid ? acc[jj] : 0.f;
        float s = bfly64(v);
        float q = bfly64(v * v);
        if (lane == jj) atomicAdd(&sAr[jj], s);
        if (lane == 32 + jj) atomicAdd(&sAr[32 + jj], q);
    }
    __syncthreads();
    if (tid < 64) atomicAdd(&sums[tid], (double)sAr[tid]);
}

// ---------------- per-node BN+ReLU apply: h -> b (fp16), once per node ----------------
template<int F>
__global__ __launch_bounds__(256)
void bn_apply(const uint4* __restrict__ h, const double* __restrict__ sums,
              const float* __restrict__ gamma, const float* __restrict__ beta,
              uint4* __restrict__ out, int N) {
    __shared__ __align__(16) float lsc[F], lsf[F];
    int tid = threadIdx.x;
    if (tid < F) {
        double mu = sums[tid] / (double)N_NODES;
        double var = sums[F + tid] / (double)N_NODES - mu * mu;
        if (var < 0.0) var = 0.0;
        double sc = (double)gamma[tid] / sqrt(var + BN_EPS);
        lsc[tid] = (float)sc;
        lsf[tid] = (float)((double)beta[tid] - mu * sc);
    }
    __syncthreads();
    constexpr int FV = F / 8;
    int total = N * FV;
    for (int i = blockIdx.x * 256 + tid; i < total; i += gridDim.x * 256) {
        uint4 v = h[i];
        int c4 = (i & (FV - 1)) * 2;      // float4 index of first quad
        float4 sca = ((const float4*)lsc)[c4];
        float4 scb = ((const float4*)lsc)[c4 + 1];
        float4 sfa = ((const float4*)lsf)[c4];
        float4 sfb = ((const float4*)lsf)[c4 + 1];
        float2 f0 = unpack_h2(v.x), f1 = unpack_h2(v.y);
        float2 f2 = unpack_h2(v.z), f3 = unpack_h2(v.w);
        uint4 o;
        o.x = pack_h2(fmaxf(f0.x * sca.x + sfa.x, 0.f), fmaxf(f0.y * sca.y + sfa.y, 0.f));
        o.y = pack_h2(fmaxf(f1.x * sca.z + sfa.z, 0.f), fmaxf(f1.y * sca.w + sfa.w, 0.f));
        o.z = pack_h2(fmaxf(f2.x * scb.x + sfb.x, 0.f), fmaxf(f2.y * scb.y + sfb.y, 0.f));
        o.w = pack_h2(fmaxf(f3.x * scb.z + sfb.z, 0.f), fmaxf(f3.y * scb.w + sfb.w, 0.f));
        out[i] = o;
    }
}

// ---------------- fp16 sum-gather agg, 16-deep MLP, fp32 dual-bank accum ----------------
__device__ __forceinline__ void accum8_h16(float* acc, uint4 v) {
    float2 f0 = unpack_h2(v.x), f1 = unpack_h2(v.y);
    float2 f2 = unpack_h2(v.z), f3 = unpack_h2(v.w);
    acc[0] += f0.x; acc[1] += f0.y; acc[2] += f1.x; acc[3] += f1.y;
    acc[4] += f2.x; acc[5] += f2.y; acc[6] += f3.x; acc[7] += f3.y;
}

template<int F>
__global__ __launch_bounds__(256)
void agg_sum(const uint4* __restrict__ xb, const int* __restrict__ offs,
             const int* __restrict__ oend, const int* __restrict__ nbr,
             uint4* __restrict__ aggh, int N) {
    constexpr int FV = F / 8;            // uint4 lanes per row
    constexpr int NPB = 256 / FV;        // nodes per block
    int n = blockIdx.x * NPB + threadIdx.y;
    if (n >= N) return;
    int f = threadIdx.x;
    int beg = offs[n], end = oend[n];
    float a0[8], a1[8];
#pragma unroll
    for (int q = 0; q < 8; ++q) { a0[q] = 0.f; a1[q] = 0.f; }
    int j = beg;
    // 16-deep main loop: 16 independent gathers in flight per thread
    for (; j + 16 <= end; j += 16) {
        int s[16];
#pragma unroll
        for (int u = 0; u < 16; ++u) s[u] = __builtin_nontemporal_load(nbr + j + u);
        uint4 v[16];
#pragma unroll
        for (int u = 0; u < 16; ++u) v[u] = xb[s[u] * FV + f];
#pragma unroll
        for (int u = 0; u < 16; ++u)
            accum8_h16((u & 1) ? a1 : a0, v[u]);
    }
    if (j + 8 <= end) {
        int s[8];
#pragma unroll
        for (int u = 0; u < 8; ++u) s[u] = __builtin_nontemporal_load(nbr + j + u);
        uint4 v[8];
#pragma unroll
        for (int u = 0; u < 8; ++u) v[u] = xb[s[u] * FV + f];
#pragma unroll
        for (int u = 0; u < 8; ++u)
            accum8_h16((u & 1) ? a1 : a0, v[u]);
        j += 8;
    }
    if (j + 4 <= end) {
        int s[4];
#pragma unroll
        for (int u = 0; u < 4; ++u) s[u] = __builtin_nontemporal_load(nbr + j + u);
        uint4 v[4];
#pragma unroll
        for (int u = 0; u < 4; ++u) v[u] = xb[s[u] * FV + f];
#pragma unroll
        for (int u = 0; u < 4; ++u)
            accum8_h16((u & 1) ? a1 : a0, v[u]);
        j += 4;
    }
    for (; j < end; ++j) {
        uint4 v = xb[__builtin_nontemporal_load(nbr + j) * FV + f];
        accum8_h16(a0, v);
    }
    float invd = 1.0f / fmaxf((float)(end - beg), 1.0f);
    uint4 o;
    o.x = pack_h2((a0[0] + a1[0]) * invd, (a0[1] + a1[1]) * invd);
    o.y = pack_h2((a0[2] + a1[2]) * invd, (a0[3] + a1[3]) * invd);
    o.z = pack_h2((a0[4] + a1[4]) * invd, (a0[5] + a1[5]) * invd);
    o.w = pack_h2((a0[6] + a1[6]) * invd, (a0[7] + a1[7]) * invd);
    aggh[n * FV + f] = o;
}

// ---------------- MFMA linear: pure-load fp16 fragments (agg pre-scaled, x pre-BN'd),
// split-fp16 weights, fp32 MFMA accumulate, fp16 out, fused BN-stats partials ----------------
template<int DIN, int DOUT>
__global__ __launch_bounds__(256)
void linear_mfma(const __half* __restrict__ bnx16, const __half* __restrict__ agg16,
                 const __half* __restrict__ wlhi, const __half* __restrict__ wllo,
                 const __half* __restrict__ wrhi, const __half* __restrict__ wrlo,
                 const float* __restrict__ bl,
                 __half* __restrict__ hout16, float* __restrict__ partial, int N) {
    constexpr int KB = DIN / 32;    // K-slabs of 32
    constexpr int NCB = DOUT / 16;  // col-blocks of 16
    constexpr int MREP = 2;         // 16-row fragments per wave
    constexpr int MB = 4 * MREP * 16;  // 128 rows per block
    __shared__ float blkS[DOUT], blkQ[DOUT];
    int tid = threadIdx.x;
    for (int i = tid; i < DOUT; i += 256) { blkS[i] = 0.f; blkQ[i] = 0.f; }
    __syncthreads();
    int n0 = blockIdx.x * MB;

    int wave = tid >> 6;
    int lane = tid & 63;
    int rlane = lane & 15;
    int kg = lane >> 4;          // 0..3 -> k-group of 8
    int rbase = n0 + wave * (MREP * 16);

    // ---- A fragments: pure vector loads ----
    f16x8 aA[MREP][KB], aX[MREP][KB];
#pragma unroll
    for (int m = 0; m < MREP; ++m) {
        int row = rbase + m * 16 + rlane;
        int rowc = min(row, N - 1);
#pragma unroll
        for (int kb = 0; kb < KB; ++kb) {
            int c0 = kb * 32 + kg * 8;
            F16x8u ta, tx;
            ta.u = *(const uint4*)(agg16 + (size_t)rowc * DIN + c0);
            tx.u = *(const uint4*)(bnx16 + (size_t)rowc * DIN + c0);
            aA[m][kb] = ta.v;
            aX[m][kb] = tx.v;
        }
    }

    // ---- accumulators init with bias (D layout: row=(lane>>4)*4+r, col=lane&15) ----
    f32x4 acc[MREP][NCB];
#pragma unroll
    for (int cb = 0; cb < NCB; ++cb) {
        float bv = bl[cb * 16 + rlane];
#pragma unroll
        for (int m = 0; m < MREP; ++m)
            acc[m][cb] = {bv, bv, bv, bv};
    }

    // ---- MFMA main: acc += aA*(Wl_hi+Wl_lo) + aX*(Wr_hi+Wr_lo) ----
#pragma unroll
    for (int cb = 0; cb < NCB; ++cb) {
#pragma unroll
        for (int kb = 0; kb < KB; ++kb) {
            size_t fo = ((size_t)(kb * NCB + cb) * 64 + lane) * 8;
            f16x8 blh = *(const f16x8*)(wlhi + fo);
            f16x8 bll = *(const f16x8*)(wllo + fo);
            f16x8 brh = *(const f16x8*)(wrhi + fo);
            f16x8 brl = *(const f16x8*)(wrlo + fo);
#pragma unroll
            for (int m = 0; m < MREP; ++m) {
                acc[m][cb] = __builtin_amdgcn_mfma_f32_16x16x32_f16(aA[m][kb], blh, acc[m][cb], 0, 0, 0);
                acc[m][cb] = __builtin_amdgcn_mfma_f32_16x16x32_f16(aA[m][kb], bll, acc[m][cb], 0, 0, 0);
                acc[m][cb] = __builtin_amdgcn_mfma_f32_16x16x32_f16(aX[m][kb], brh, acc[m][cb], 0, 0, 0);
                acc[m][cb] = __builtin_amdgcn_mfma_f32_16x16x32_f16(aX[m][kb], brl, acc[m][cb], 0, 0, 0);
            }
        }
    }

    // ---- store fp16 outputs ----
#pragma unroll
    for (int m = 0; m < MREP; ++m) {
        int rowb = rbase + m * 16 + kg * 4;
#pragma unroll
        for (int r = 0; r < 4; ++r) {
            int node = rowb + r;
            if (node < N) {
#pragma unroll
                for (int cb = 0; cb < NCB; ++cb)
                    hout16[(size_t)node * DOUT + cb * 16 + rlane] = __float2half(acc[m][cb][r]);
            }
        }
    }

    // ---- fused BN-stats partials: per-block sum/sumsq per feature ----
#pragma unroll
    for (int cb = 0; cb < NCB; ++cb) {
        float s = 0.f, q = 0.f;
#pragma unroll
        for (int m = 0; m < MREP; ++m) {
            int rowb = rbase + m * 16 + kg * 4;
#pragma unroll
            for (int r = 0; r < 4; ++r) {
                if (rowb + r < N) {
                    float v = acc[m][cb][r];
                    s += v; q += v * v;
                }
            }
        }
        s += __shfl_xor(s, 16, 64); s += __shfl_xor(s, 32, 64);
        q += __shfl_xor(q, 16, 64); q += __shfl_xor(q, 32, 64);
        if (kg == 0) {
            atomicAdd(&blkS[cb * 16 + rlane], s);
            atomicAdd(&blkQ[cb * 16 + rlane], q);
        }
    }
    __syncthreads();
    float* po = partial + (size_t)blockIdx.x * (2 * DOUT);
    for (int i = tid; i < DOUT; i += 256) {
        po[i] = blkS[i];
        po[DOUT + i] = blkQ[i];
    }
}

// ---------------- stats finalize: reduce P block-partials per feature in fp64, fixed order ----------------
template<int F>
__global__ __launch_bounds__(256)
void stats_finalize2(const float* __restrict__ partial, double* __restrict__ sums, int P) {
    __shared__ double sh[256];
    int i = blockIdx.x;
    int t = threadIdx.x;
    double a = 0.0;
    for (int k = t; k < P; k += 256)
        a += (double)partial[(size_t)k * (2 * F) + i];
    sh[t] = a;
    __syncthreads();
    for (int st = 128; st > 0; st >>= 1) {
        if (t < st) sh[t] += sh[t + st];
        __syncthreads();
    }
    if (t == 0) sums[i] = sh[0];
}

// ---------------- pool (fp16 h3) with inline BN3 finalize + fused ReLU ----------------
__global__ void pool_partial(const __half* __restrict__ h, const int* __restrict__ batch,
                             const double* __restrict__ sums,
                             const float* __restrict__ gamma, const float* __restrict__ beta,
                             double* __restrict__ pooled_d, int N) {
    __shared__ float lsc[128], lsf[128];
    const int CH = 64;
    int f = threadIdx.x;
    {
        double mu = sums[f] / (double)N_NODES;
        double var = sums[128 + f] / (double)N_NODES - mu * mu;
        if (var < 0.0) var = 0.0;
        double sc = (double)gamma[f] / sqrt(var + BN_EPS);
        lsc[f] = (float)sc;
        lsf[f] = (float)((double)beta[f] - mu * sc);
    }
    __syncthreads();
    int n0 = blockIdx.x * CH;
    if (n0 >= N) return;
    int n1 = min(n0 + CH, N);
    float sc = lsc[f], sf = lsf[f];
    int g = batch[n0];
    float acc = 0.f;
    for (int n = n0; n < n1; ++n) {
        int bg = batch[n];
        if (bg != g) {
            atomicAdd(&pooled_d[g * 128 + f], (double)acc);
            acc = 0.f;
            g = bg;
        }
        float v = __half2float(h[(long long)n * 128 + f]);
        acc += fmaxf(v * sc + sf, 0.f);
    }
    atomicAdd(&pooled_d[g * 128 + f], (double)acc);
}

// ---------------- fused pool-finalize + head MLP ----------------
__global__ void mlp_fused(const double* __restrict__ pooled_d, const int* __restrict__ batch,
                          const float* __restrict__ Wf1, const float* __restrict__ bf1,
                          const float* __restrict__ Wf2, const float* __restrict__ bf2,
                          float* __restrict__ out, int N) {
    __shared__ float sp[128];
    int g = blockIdx.x;
    int t = threadIdx.x;
    int lo = 0, hi = N;
    while (lo < hi) { int m = (lo + hi) >> 1; if (batch[m] < g) lo = m + 1; else hi = m; }
    int start = lo;
    hi = N;
    while (lo < hi) { int m = (lo + hi) >> 1; if (batch[m] < g + 1) lo = m + 1; else hi = m; }
    int cnt = lo - start;
    sp[t] = (float)(pooled_d[g * 128 + t] / (double)max(cnt, 1));
    __syncthreads();
    if (t < 64) {
        float hacc = bf1[t];
#pragma unroll 8
        for (int k = 0; k < 128; ++k) hacc += sp[k] * Wf1[k * 64 + t];
        hacc = fmaxf(hacc, 0.f) * Wf2[t];
        for (int o = 32; o > 0; o >>= 1) hacc += __shfl_down(hacc, o);
        if (t == 0) out[g] = hacc + bf2[0];
    }
}

extern "C" void kernel_launch(void* const* d_in, const int* in_sizes, int n_in,
                              void* d_out, int out_size, void* d_ws, size_t ws_size,
                              hipStream_t stream) {
    const float* x     = (const float*)d_in[0];
    const int*   ei    = (const int*)d_in[1];
    const int*   batch = (const int*)d_in[2];
    const float *Wl1=(const float*)d_in[3],  *bl1=(const float*)d_in[4],  *Wr1=(const float*)d_in[5];
    const float *g1 =(const float*)d_in[6],  *be1=(const float*)d_in[7];
    const float *Wl2=(const float*)d_in[8],  *bl2=(const float*)d_in[9],  *Wr2=(const float*)d_in[10];
    const float *g2 =(const float*)d_in[11], *be2=(const float*)d_in[12];
    const float *Wl3=(const float*)d_in[13], *bl3=(const float*)d_in[14], *Wr3=(const float*)d_in[15];
    const float *g3 =(const float*)d_in[16], *be3=(const float*)d_in[17];
    const float *Wf1=(const float*)d_in[18], *bf1=(const float*)d_in[19];
    const float *Wf2=(const float*)d_in[20], *bf2=(const float*)d_in[21];

    const int N = N_NODES;
    const int E = in_sizes[1] / 2;
    const int* src = ei;
    const int* dst = ei + E;

    char* ws = (char*)d_ws;
    size_t off = 0;
    auto salloc = [&](size_t bytes) {
        void* p = ws + off;
        off += (bytes + 255) & ~(size_t)255;
        return p;
    };
    // --- zeroed-in-pack_w region (must stay contiguous: sums then pooledd) ---
    double* sums    = (double*)salloc(768 * 8);                      // 6144 B (256-aligned)
    double* pooledd = (double*)salloc((size_t)N_GRAPHS * 128 * 8);   // 65536 B
    // --- rest ---
    int*    offs    = (int*)   salloc((size_t)N * 4);
    int*    oend    = (int*)   salloc((size_t)N * 4);
    int*    fcur    = (int*)   salloc((NBF + 1) * 4);
    int*    nbr     = (int*)   salloc((size_t)NBF * CAPF * 4);       // 7.2 MB (padded bucket regions)
    float*  partial = (float*) salloc((size_t)1024 * 256 * 4);       // 1 MB (stats partials)
    __half* pk      = (__half*)salloc((size_t)40960 * 2);            // 80 KB packed weights
    __half* h1h     = (__half*)salloc((size_t)(N + 256) * 32 * 2);   // 6.4 MB
    __half* b1h     = (__half*)salloc((size_t)(N + 256) * 32 * 2);   // 6.4 MB bnrelu(h1)
    __half* h2h     = (__half*)salloc((size_t)(N + 256) * 64 * 2);   // 12.8 MB
    __half* b2h     = (__half*)salloc((size_t)(N + 256) * 64 * 2);   // 12.8 MB bnrelu(h2)
    __half* h3h     = (__half*)salloc((size_t)(N + 256) * 128 * 2);  // 25.7 MB
    __half* aggh    = (__half*)salloc((size_t)(N + 256) * 64 * 2);   // 12.8 MB (hosts qpk early)
    (void)ws_size;

    double* sums1 = sums, *sums2 = sums + 256, *sums3 = sums + 512;
    int* qpk = (int*)aggh;                 // 391*CAPF*4 = 7.2 MB <= 12.8

    const __half *pwl2h = pk,         *pwl2l = pk + 2048;
    const __half *pwr2h = pk + 4096,  *pwr2l = pk + 6144;
    const __half *pwl3h = pk + 8192,  *pwl3l = pk + 16384;
    const __half *pwr3h = pk + 24576, *pwr3l = pk + 32768;

    // ---- weight packing + cursor init + zero-init (fused, tiny) ----
    pack_w<<<80, 256, 0, stream>>>(Wl2, Wr2, Wl3, Wr3, pk, fcur, sums);

    // ---- CSR build: single-pass partition into 391 fixed-capacity buckets ----
    part1<<<(E + PT1 - 1) / PT1, 256, 0, stream>>>(dst, src, fcur, qpk, E);
    fill_final<<<NBF, 256, 0, stream>>>(qpk, fcur, offs, oend, nbr, N);

    const int NL = (N + 255) / 256;
    const int NBLK = (N + 127) / 128;   // 782 blocks for linear_mfma

    // ---- layer 1: fused agg + linear + stats -> fp16 h1 ----
    layer1_fused<<<NL, 256, 0, stream>>>((const float2*)x, offs, oend, nbr,
                                          Wl1, bl1, Wr1, h1h, sums1, N);

    // ---- layer 2 ----
    bn_apply<32><<<512, 256, 0, stream>>>((const uint4*)h1h, sums1, g1, be1, (uint4*)b1h, N);
    agg_sum<32><<<(N + 63) / 64, dim3(4, 64), 0, stream>>>(
        (const uint4*)b1h, offs, oend, nbr, (uint4*)aggh, N);
    linear_mfma<32, 64><<<NBLK, 256, 0, stream>>>(
        b1h, (const __half*)aggh, pwl2h, pwl2l, pwr2h, pwr2l, bl2, h2h, partial, N);
    stats_finalize2<64><<<128, 256, 0, stream>>>(partial, sums2, NBLK);

    // ---- layer 3 ----
    bn_apply<64><<<512, 256, 0, stream>>>((const uint4*)h2h, sums2, g2, be2, (uint4*)b2h, N);
    agg_sum<64><<<(N + 31) / 32, dim3(8, 32), 0, stream>>>(
        (const uint4*)b2h, offs, oend, nbr, (uint4*)aggh, N);
    linear_mfma<64, 128><<<NBLK, 256, 0, stream>>>(
        b2h, (const __half*)aggh, pwl3h, pwl3l, pwr3h, pwr3l, bl3, h3h, partial, N);
    stats_finalize2<128><<<256, 256, 0, stream>>>(partial, sums3, NBLK);

    // ---- pool + head ----
    pool_partial<<<(N + 63) / 64, 128, 0, stream>>>(h3h, batch, sums3, g3, be3, pooledd, N);
    mlp_fused<<<N_GRAPHS, 128, 0, stream>>>(pooledd, batch, Wf1, bf1, Wf2, bf2, (float*)d_out, N);
}